// Round 1
// baseline (284.161 us; speedup 1.0000x reference)
//
#include <hip/hip_runtime.h>

typedef __attribute__((ext_vector_type(8))) short short8;
typedef __attribute__((ext_vector_type(4))) float f32x4;

#define B_  2
#define S_  2048
#define D_  1024
#define H_  16
#define HD_ 64
#define M_  (B_*S_)                    // 4096
#define N_  (H_*HD_)                   // 1024
#define HSZ ((size_t)B_*H_*S_*HD_)     // 4194304 elements per Q/K/V

// f32 -> bf16 round-to-nearest-even
__device__ __forceinline__ unsigned short f2bf(float f) {
  unsigned int u = __float_as_uint(f);
  u += 0x7fffu + ((u >> 16) & 1u);
  return (unsigned short)(u >> 16);
}

// ---- convert X [4096][1024] f32 -> bf16 row-major ----
__global__ void cvt_x_kernel(const float* __restrict__ x, unsigned short* __restrict__ xb) {
  int i = blockIdx.x * blockDim.x + threadIdx.x;
  float4 v = reinterpret_cast<const float4*>(x)[i];
  ushort4 o;
  o.x = f2bf(v.x); o.y = f2bf(v.y); o.z = f2bf(v.z); o.w = f2bf(v.w);
  reinterpret_cast<ushort4*>(xb)[i] = o;
}

// ---- convert W [1024][1024] f32 -> Wt bf16 with Wt[n][k] = W[k][n] ----
__global__ void cvt_w_transpose_kernel(const float* __restrict__ w0, const float* __restrict__ w1,
                                       const float* __restrict__ w2, unsigned short* __restrict__ wt) {
  __shared__ float tile[32][33];
  const float* w = blockIdx.z == 0 ? w0 : (blockIdx.z == 1 ? w1 : w2);
  unsigned short* o = wt + (size_t)blockIdx.z * D_ * N_;
  int kbase = blockIdx.y * 32, nbase = blockIdx.x * 32;
#pragma unroll
  for (int i = 0; i < 4; i++)
    tile[threadIdx.y + i*8][threadIdx.x] =
        w[(size_t)(kbase + threadIdx.y + i*8) * N_ + nbase + threadIdx.x];
  __syncthreads();
#pragma unroll
  for (int i = 0; i < 4; i++)
    o[(size_t)(nbase + threadIdx.y + i*8) * D_ + kbase + threadIdx.x] =
        f2bf(tile[threadIdx.x][threadIdx.y + i*8]);
}

// ---- QKV GEMM: C[m][n] = X[m][:] . W[:][n], out -> qkv[mat][b][h][s][d] bf16 ----
// 128x128 block tile, 4 waves of 64x64, mfma 16x16x32 bf16.
__global__ __launch_bounds__(256) void qkv_gemm_kernel(const unsigned short* __restrict__ xb,
                                                       const unsigned short* __restrict__ wt,
                                                       unsigned short* __restrict__ qkv) {
  const unsigned short* w = wt + (size_t)blockIdx.z * D_ * N_;
  unsigned short* out = qkv + (size_t)blockIdx.z * HSZ;
  int lane = threadIdx.x & 63, wave = threadIdx.x >> 6;
  int lr = lane & 15, lk = lane >> 4;
  int mbase = blockIdx.y * 128 + (wave >> 1) * 64;
  int nbase = blockIdx.x * 128 + (wave & 1) * 64;
  f32x4 acc[4][4] = {};
  for (int kk = 0; kk < D_; kk += 32) {
    short8 a[4], b[4];
#pragma unroll
    for (int i = 0; i < 4; i++)
      a[i] = *reinterpret_cast<const short8*>(xb + (size_t)(mbase + i*16 + lr) * D_ + kk + lk*8);
#pragma unroll
    for (int j = 0; j < 4; j++)
      b[j] = *reinterpret_cast<const short8*>(w + (size_t)(nbase + j*16 + lr) * D_ + kk + lk*8);
#pragma unroll
    for (int i = 0; i < 4; i++)
#pragma unroll
      for (int j = 0; j < 4; j++)
        acc[i][j] = __builtin_amdgcn_mfma_f32_16x16x32_bf16(a[i], b[j], acc[i][j], 0, 0, 0);
  }
#pragma unroll
  for (int i = 0; i < 4; i++)
#pragma unroll
    for (int j = 0; j < 4; j++)
#pragma unroll
      for (int r = 0; r < 4; r++) {
        int m = mbase + i*16 + lk*4 + r;          // global row in [B*S]
        int n = nbase + j*16 + lr;                // global col in [H*HD]
        int bb = m >> 11, s = m & (S_-1), h = n >> 6, d = n & (HD_-1);
        out[(((size_t)bb * H_ + h) * S_ + s) * HD_ + d] = f2bf(acc[i][j][r]);
      }
}

// ---- Flash attention: 64 Q-rows / block, KV tile = 64, online softmax ----
__global__ __launch_bounds__(256) void attn_kernel(const unsigned short* __restrict__ qkv,
                                                   float* __restrict__ out) {
  int bh = blockIdx.y;
  const unsigned short* Q = qkv +            (size_t)bh * S_ * HD_;
  const unsigned short* K = qkv + HSZ   +    (size_t)bh * S_ * HD_;
  const unsigned short* V = qkv + 2*HSZ +    (size_t)bh * S_ * HD_;
  int lane = threadIdx.x & 63, wave = threadIdx.x >> 6;
  int lr = lane & 15, lk = lane >> 4;
  int qbase = blockIdx.x * 64 + wave * 16;   // this wave's 16 Q rows

  __shared__ unsigned short vt[64][64];        // V^T tile: vt[d][kcol]
  __shared__ unsigned short p_lds[4][16][64];  // per-wave P tile

  // Q fragments held in registers for the whole pass
  short8 qf[2];
#pragma unroll
  for (int ks = 0; ks < 2; ks++)
    qf[ks] = *reinterpret_cast<const short8*>(Q + (size_t)(qbase + lr) * HD_ + ks*32 + lk*8);

  f32x4 oacc[4] = {};
  float mrow[4], lsum[4];
#pragma unroll
  for (int r = 0; r < 4; r++) { mrow[r] = -INFINITY; lsum[r] = 0.f; }

  int vrow = threadIdx.x >> 2;          // 0..63
  int vcol = (threadIdx.x & 3) * 16;    // 0,16,32,48

  for (int kt = 0; kt < S_/64; kt++) {
    int kc0 = kt * 64;
    __syncthreads();                    // previous PV done reading vt
    // stage V^T into LDS
    {
      const unsigned short* vr = V + (size_t)(kc0 + vrow) * HD_ + vcol;
      short8 v0 = *reinterpret_cast<const short8*>(vr);
      short8 v1 = *reinterpret_cast<const short8*>(vr + 8);
#pragma unroll
      for (int i = 0; i < 8; i++) vt[vcol + i][vrow]     = (unsigned short)v0[i];
#pragma unroll
      for (int i = 0; i < 8; i++) vt[vcol + 8 + i][vrow] = (unsigned short)v1[i];
    }
    // QK^T: S_tile[16 q][64 k] per wave (K frags straight from global/L2)
    f32x4 sacc[4] = {};
#pragma unroll
    for (int j = 0; j < 4; j++)
#pragma unroll
      for (int ks = 0; ks < 2; ks++) {
        short8 kf = *reinterpret_cast<const short8*>(
            K + (size_t)(kc0 + j*16 + lr) * HD_ + ks*32 + lk*8);
        sacc[j] = __builtin_amdgcn_mfma_f32_16x16x32_bf16(qf[ks], kf, sacc[j], 0, 0, 0);
      }
    __syncthreads();                    // vt ready

    // online softmax: row m = qbase + lk*4 + r lives on the 16 lanes sharing lk
    unsigned short pbf[4][4];
#pragma unroll
    for (int r = 0; r < 4; r++) {
      float s0 = sacc[0][r]*0.125f, s1 = sacc[1][r]*0.125f,
            s2 = sacc[2][r]*0.125f, s3 = sacc[3][r]*0.125f;
      float mx = fmaxf(fmaxf(s0, s1), fmaxf(s2, s3));
#pragma unroll
      for (int msk = 1; msk < 16; msk <<= 1) mx = fmaxf(mx, __shfl_xor(mx, msk));
      float mnew = fmaxf(mrow[r], mx);
      float corr = __expf(mrow[r] - mnew);   // first tile: exp(-inf) = 0
      mrow[r] = mnew;
      float p0 = __expf(s0 - mnew), p1 = __expf(s1 - mnew),
            p2 = __expf(s2 - mnew), p3 = __expf(s3 - mnew);
      pbf[0][r] = f2bf(p0); pbf[1][r] = f2bf(p1);
      pbf[2][r] = f2bf(p2); pbf[3][r] = f2bf(p3);
      float rs = p0 + p1 + p2 + p3;
#pragma unroll
      for (int msk = 1; msk < 16; msk <<= 1) rs += __shfl_xor(rs, msk);
      lsum[r] = lsum[r] * corr + rs;
#pragma unroll
      for (int jd = 0; jd < 4; jd++) oacc[jd][r] *= corr;
    }
    // stage P (wave-private region; same-wave LDS RAW handled by lgkmcnt)
#pragma unroll
    for (int j = 0; j < 4; j++)
#pragma unroll
      for (int r = 0; r < 4; r++)
        p_lds[wave][lk*4 + r][j*16 + lr] = pbf[j][r];

    // PV: O[16 q][64 d] += P[16 q][64 k] * V[64 k][64 d]
#pragma unroll
    for (int ks = 0; ks < 2; ks++) {
      short8 pf = *reinterpret_cast<const short8*>(&p_lds[wave][lr][ks*32 + lk*8]);
#pragma unroll
      for (int jd = 0; jd < 4; jd++) {
        short8 vf = *reinterpret_cast<const short8*>(&vt[jd*16 + lr][ks*32 + lk*8]);
        oacc[jd] = __builtin_amdgcn_mfma_f32_16x16x32_bf16(pf, vf, oacc[jd], 0, 0, 0);
      }
    }
  }

  int b0 = bh >> 4, h = bh & (H_-1);
#pragma unroll
  for (int jd = 0; jd < 4; jd++)
#pragma unroll
    for (int r = 0; r < 4; r++) {
      int s = qbase + lk*4 + r;
      int d = jd*16 + lr;
      out[((size_t)b0 * S_ + s) * N_ + h*HD_ + d] = oacc[jd][r] / lsum[r];
    }
}

extern "C" void kernel_launch(void* const* d_in, const int* in_sizes, int n_in,
                              void* d_out, int out_size, void* d_ws, size_t ws_size,
                              hipStream_t stream) {
  const float* X  = (const float*)d_in[0];
  const float* Wq = (const float*)d_in[1];
  const float* Wk = (const float*)d_in[2];
  const float* Wv = (const float*)d_in[3];
  float* out = (float*)d_out;

  // workspace layout (bf16 as ushort): Xb | Wt(3) | QKV(3)  ~= 39.8 MB
  unsigned short* Xb  = (unsigned short*)d_ws;
  unsigned short* Wt  = Xb + (size_t)M_ * D_;
  unsigned short* QKV = Wt + (size_t)3 * D_ * N_;

  cvt_x_kernel<<<(M_*D_)/(256*4), 256, 0, stream>>>(X, Xb);
  cvt_w_transpose_kernel<<<dim3(N_/32, D_/32, 3), dim3(32, 8), 0, stream>>>(Wq, Wk, Wv, Wt);
  qkv_gemm_kernel<<<dim3(N_/128, M_/128, 3), 256, 0, stream>>>(Xb, Wt, QKV);
  attn_kernel<<<dim3(S_/64, B_*H_), 256, 0, stream>>>(QKV, out);
}

// Round 2
// 225.229 us; speedup vs baseline: 1.2617x; 1.2617x over previous
//
#include <hip/hip_runtime.h>

typedef __attribute__((ext_vector_type(8))) short short8;
typedef __attribute__((ext_vector_type(4))) float f32x4;

#define B_  2
#define S_  2048
#define D_  1024
#define H_  16
#define HD_ 64
#define M_  (B_*S_)                    // 4096
#define N_  (H_*HD_)                   // 1024
#define HSZ ((size_t)B_*H_*S_*HD_)     // 4194304 elements per Q/K/V

// XOR swizzle for 128-byte LDS rows: spreads both {16 consecutive rows} (read
// conflict set) and {rows differing by 16/4} (write conflict sets) across 16B slots.
#define SWZ(r) ((((r) & 7) ^ (((r) >> 3) & 7)) << 4)

__device__ __forceinline__ unsigned short f2bf(float f) {
  unsigned int u = __float_as_uint(f);
  u += 0x7fffu + ((u >> 16) & 1u);
  return (unsigned short)(u >> 16);
}

__device__ __forceinline__ void gll16(const void* g, void* l) {
  __builtin_amdgcn_global_load_lds(
      (const __attribute__((address_space(1))) void*)g,
      (__attribute__((address_space(3))) void*)l, 16, 0, 0);
}

// ---- convert X [4096][1024] f32 -> bf16 row-major ----
__global__ void cvt_x_kernel(const float* __restrict__ x, unsigned short* __restrict__ xb) {
  int i = blockIdx.x * blockDim.x + threadIdx.x;
  float4 v = reinterpret_cast<const float4*>(x)[i];
  ushort4 o;
  o.x = f2bf(v.x); o.y = f2bf(v.y); o.z = f2bf(v.z); o.w = f2bf(v.w);
  reinterpret_cast<ushort4*>(xb)[i] = o;
}

// ---- convert W [1024][1024] f32 -> Wt bf16 with Wt[n][k] = W[k][n] ----
__global__ void cvt_w_transpose_kernel(const float* __restrict__ w0, const float* __restrict__ w1,
                                       const float* __restrict__ w2, unsigned short* __restrict__ wt) {
  __shared__ float tile[32][33];
  const float* w = blockIdx.z == 0 ? w0 : (blockIdx.z == 1 ? w1 : w2);
  unsigned short* o = wt + (size_t)blockIdx.z * D_ * N_;
  int kbase = blockIdx.y * 32, nbase = blockIdx.x * 32;
#pragma unroll
  for (int i = 0; i < 4; i++)
    tile[threadIdx.y + i*8][threadIdx.x] =
        w[(size_t)(kbase + threadIdx.y + i*8) * N_ + nbase + threadIdx.x];
  __syncthreads();
#pragma unroll
  for (int i = 0; i < 4; i++)
    o[(size_t)(nbase + threadIdx.y + i*8) * D_ + kbase + threadIdx.x] =
        f2bf(tile[threadIdx.x][threadIdx.y + i*8]);
}

// ---- QKV GEMM, m97-style: 128x128 tile, BK=64, global_load_lds staging ----
// LDS [128 rows][64 cols] bf16 per operand, col-chunk XOR-swizzled by (row&7):
// linear LDS dest (rule #21) + pre-swizzled global source + swizzled ds_read.
__global__ __launch_bounds__(256) void qkv_gemm_kernel(const unsigned short* __restrict__ xb,
                                                       const unsigned short* __restrict__ wt,
                                                       unsigned short* __restrict__ qkv) {
  __shared__ __align__(16) unsigned short As[128 * 64];  // 16 KB
  __shared__ __align__(16) unsigned short Bs[128 * 64];  // 16 KB
  const unsigned short* w = wt + (size_t)blockIdx.z * D_ * N_;
  unsigned short* out = qkv + (size_t)blockIdx.z * HSZ;
  int lane = threadIdx.x & 63, wave = threadIdx.x >> 6;
  int lr = lane & 15, lk = lane >> 4;
  int mblk = blockIdx.y * 128, nblk = blockIdx.x * 128;
  int wm = (wave >> 1) * 64, wn = (wave & 1) * 64;

  // staging: chunk c = wave*4 + it covers LDS bytes c*1024..+1023 = rows c*8..c*8+7
  int srow0 = wave * 32 + (lane >> 3);   // row for it=0 (+8 per it)
  int scol = lane & 7;                   // 16B col-chunk within row
  f32x4 acc[4][4] = {};

  for (int kk = 0; kk < D_; kk += 64) {
    __syncthreads();   // previous iteration's fragment reads complete
#pragma unroll
    for (int it = 0; it < 4; it++) {
      int row = srow0 + it * 8;
      int ce = (scol ^ (row & 7)) * 8;   // pre-swizzled source col (elements)
      gll16(xb + (size_t)(mblk + row) * D_ + kk + ce,
            (void*)(As + (size_t)(wave * 4 + it) * 512));
      gll16(w  + (size_t)(nblk + row) * D_ + kk + ce,
            (void*)(Bs + (size_t)(wave * 4 + it) * 512));
    }
    __syncthreads();   // tiles ready (compiler drains vmcnt before barrier)

    short8 a[2][4], b[2][4];
#pragma unroll
    for (int i = 0; i < 4; i++) {
      int row = wm + i * 16 + lr;
      const char* rp = (const char*)As + row * 128;
#pragma unroll
      for (int ks = 0; ks < 2; ks++)
        a[ks][i] = *reinterpret_cast<const short8*>(rp + ((((ks*4 + lk) ^ (row & 7))) << 4));
    }
#pragma unroll
    for (int j = 0; j < 4; j++) {
      int row = wn + j * 16 + lr;
      const char* rp = (const char*)Bs + row * 128;
#pragma unroll
      for (int ks = 0; ks < 2; ks++)
        b[ks][j] = *reinterpret_cast<const short8*>(rp + ((((ks*4 + lk) ^ (row & 7))) << 4));
    }
#pragma unroll
    for (int ks = 0; ks < 2; ks++)
#pragma unroll
      for (int i = 0; i < 4; i++)
#pragma unroll
        for (int j = 0; j < 4; j++)
          acc[i][j] = __builtin_amdgcn_mfma_f32_16x16x32_bf16(a[ks][i], b[ks][j], acc[i][j], 0, 0, 0);
  }

#pragma unroll
  for (int i = 0; i < 4; i++)
#pragma unroll
    for (int j = 0; j < 4; j++)
#pragma unroll
      for (int r = 0; r < 4; r++) {
        int m = mblk + wm + i*16 + lk*4 + r;      // global row in [B*S]
        int n = nblk + wn + j*16 + lr;            // global col in [H*HD]
        int bb = m >> 11, s = m & (S_-1), h = n >> 6, d = n & (HD_-1);
        out[(((size_t)bb * H_ + h) * S_ + s) * HD_ + d] = f2bf(acc[i][j][r]);
      }
}

// ---- Flash attention: 64 Q-rows / block, KV tile = 64, online softmax ----
__global__ __launch_bounds__(256) void attn_kernel(const unsigned short* __restrict__ qkv,
                                                   float* __restrict__ out) {
  int bh = blockIdx.y;
  const unsigned short* Q = qkv +            (size_t)bh * S_ * HD_;
  const unsigned short* K = qkv + HSZ   +    (size_t)bh * S_ * HD_;
  const unsigned short* V = qkv + 2*HSZ +    (size_t)bh * S_ * HD_;
  int lane = threadIdx.x & 63, wave = threadIdx.x >> 6;
  int lr = lane & 15, lk = lane >> 4;
  int qbase = blockIdx.x * 64 + wave * 16;   // this wave's 16 Q rows

  __shared__ __align__(16) unsigned short vt[64 * 64];        // V^T tile (swizzled rows)
  __shared__ __align__(16) unsigned short p_lds[4 * 16 * 64]; // per-wave P tile (swizzled)
  char* vbase = (char*)vt;
  char* pbase = (char*)p_lds + wave * 2048;

  short8 qf[2];
#pragma unroll
  for (int ks = 0; ks < 2; ks++)
    qf[ks] = *reinterpret_cast<const short8*>(Q + (size_t)(qbase + lr) * HD_ + ks*32 + lk*8);

  f32x4 oacc[4] = {};
  float mrow[4], lsum[4];
#pragma unroll
  for (int r = 0; r < 4; r++) { mrow[r] = -INFINITY; lsum[r] = 0.f; }

  int vrow = threadIdx.x >> 2;          // kv row this thread stages: 0..63
  int vcol = (threadIdx.x & 3) * 16;    // d-chunk: 0,16,32,48

  for (int kt = 0; kt < S_/64; kt++) {
    int kc0 = kt * 64;
    __syncthreads();                    // previous PV done reading vt
    // stage V^T into LDS (swizzled scatter)
    {
      const unsigned short* vr = V + (size_t)(kc0 + vrow) * HD_ + vcol;
      short8 v0 = *reinterpret_cast<const short8*>(vr);
      short8 v1 = *reinterpret_cast<const short8*>(vr + 8);
#pragma unroll
      for (int i = 0; i < 8; i++) {
        int r0 = vcol + i, r1 = vcol + 8 + i;
        *(unsigned short*)(vbase + r0*128 + ((vrow*2) ^ SWZ(r0))) = (unsigned short)v0[i];
        *(unsigned short*)(vbase + r1*128 + ((vrow*2) ^ SWZ(r1))) = (unsigned short)v1[i];
      }
    }
    // QK^T: S_tile[16 q][64 k] per wave (K frags straight from global/L2)
    f32x4 sacc[4] = {};
#pragma unroll
    for (int j = 0; j < 4; j++)
#pragma unroll
      for (int ks = 0; ks < 2; ks++) {
        short8 kf = *reinterpret_cast<const short8*>(
            K + (size_t)(kc0 + j*16 + lr) * HD_ + ks*32 + lk*8);
        sacc[j] = __builtin_amdgcn_mfma_f32_16x16x32_bf16(qf[ks], kf, sacc[j], 0, 0, 0);
      }
    __syncthreads();                    // vt ready

    // online softmax across the 16 lanes sharing lk
    unsigned short pbf[4][4];
#pragma unroll
    for (int r = 0; r < 4; r++) {
      float s0 = sacc[0][r]*0.125f, s1 = sacc[1][r]*0.125f,
            s2 = sacc[2][r]*0.125f, s3 = sacc[3][r]*0.125f;
      float mx = fmaxf(fmaxf(s0, s1), fmaxf(s2, s3));
#pragma unroll
      for (int msk = 1; msk < 16; msk <<= 1) mx = fmaxf(mx, __shfl_xor(mx, msk));
      float mnew = fmaxf(mrow[r], mx);
      float corr = __expf(mrow[r] - mnew);
      mrow[r] = mnew;
      float p0 = __expf(s0 - mnew), p1 = __expf(s1 - mnew),
            p2 = __expf(s2 - mnew), p3 = __expf(s3 - mnew);
      pbf[0][r] = f2bf(p0); pbf[1][r] = f2bf(p1);
      pbf[2][r] = f2bf(p2); pbf[3][r] = f2bf(p3);
      float rs = p0 + p1 + p2 + p3;
#pragma unroll
      for (int msk = 1; msk < 16; msk <<= 1) rs += __shfl_xor(rs, msk);
      lsum[r] = lsum[r] * corr + rs;
#pragma unroll
      for (int jd = 0; jd < 4; jd++) oacc[jd][r] *= corr;
    }
    // stage P (wave-private region, swizzled)
#pragma unroll
    for (int j = 0; j < 4; j++)
#pragma unroll
      for (int r = 0; r < 4; r++) {
        int row = lk*4 + r;
        *(unsigned short*)(pbase + row*128 + (((j*16 + lr)*2) ^ SWZ(row))) = pbf[j][r];
      }

    // PV: O[16 q][64 d] += P[16 q][64 k] * V[64 k][64 d]
#pragma unroll
    for (int ks = 0; ks < 2; ks++) {
      short8 pf = *reinterpret_cast<const short8*>(
          pbase + lr*128 + ((ks*64 + lk*16) ^ SWZ(lr)));
#pragma unroll
      for (int jd = 0; jd < 4; jd++) {
        int row = jd*16 + lr;
        short8 vf = *reinterpret_cast<const short8*>(
            vbase + row*128 + ((ks*64 + lk*16) ^ SWZ(row)));
        oacc[jd] = __builtin_amdgcn_mfma_f32_16x16x32_bf16(pf, vf, oacc[jd], 0, 0, 0);
      }
    }
  }

  int b0 = bh >> 4, h = bh & (H_-1);
#pragma unroll
  for (int jd = 0; jd < 4; jd++)
#pragma unroll
    for (int r = 0; r < 4; r++) {
      int s = qbase + lk*4 + r;
      int d = jd*16 + lr;
      out[((size_t)b0 * S_ + s) * N_ + h*HD_ + d] = oacc[jd][r] / lsum[r];
    }
}

extern "C" void kernel_launch(void* const* d_in, const int* in_sizes, int n_in,
                              void* d_out, int out_size, void* d_ws, size_t ws_size,
                              hipStream_t stream) {
  const float* X  = (const float*)d_in[0];
  const float* Wq = (const float*)d_in[1];
  const float* Wk = (const float*)d_in[2];
  const float* Wv = (const float*)d_in[3];
  float* out = (float*)d_out;

  unsigned short* Xb  = (unsigned short*)d_ws;
  unsigned short* Wt  = Xb + (size_t)M_ * D_;
  unsigned short* QKV = Wt + (size_t)3 * D_ * N_;

  cvt_x_kernel<<<(M_*D_)/(256*4), 256, 0, stream>>>(X, Xb);
  cvt_w_transpose_kernel<<<dim3(N_/32, D_/32, 3), dim3(32, 8), 0, stream>>>(Wq, Wk, Wv, Wt);
  qkv_gemm_kernel<<<dim3(N_/128, M_/128, 3), 256, 0, stream>>>(Xb, Wt, QKV);
  attn_kernel<<<dim3(S_/64, B_*H_), 256, 0, stream>>>(QKV, out);
}

// Round 3
// 142.636 us; speedup vs baseline: 1.9922x; 1.5790x over previous
//
#include <hip/hip_runtime.h>

typedef __attribute__((ext_vector_type(8))) short short8;
typedef __attribute__((ext_vector_type(4))) float f32x4;
typedef __attribute__((ext_vector_type(16))) float f32x16;

#define B_  2
#define S_  2048
#define D_  1024
#define H_  16
#define HD_ 64
#define M_  (B_*S_)                    // 4096
#define N_  (H_*HD_)                   // 1024
#define HSZ ((size_t)B_*H_*S_*HD_)     // 4194304 elements per Q/K/V

// XOR swizzle for 128-byte LDS rows (chunks of 16B).
#define SWZ(r) ((((r) & 7) ^ (((r) >> 3) & 7)) << 4)

__device__ __forceinline__ unsigned short f2bf(float f) {
  unsigned int u = __float_as_uint(f);
  u += 0x7fffu + ((u >> 16) & 1u);
  return (unsigned short)(u >> 16);
}

__device__ __forceinline__ unsigned int cvt_pk_bf16(float lo, float hi) {
  unsigned int r;
  asm("v_cvt_pk_bf16_f32 %0, %1, %2" : "=v"(r) : "v"(lo), "v"(hi));
  return r;
}

__device__ __forceinline__ void gll16(const void* g, void* l) {
  __builtin_amdgcn_global_load_lds(
      (const __attribute__((address_space(1))) void*)g,
      (__attribute__((address_space(3))) void*)l, 16, 0, 0);
}

// ---- convert X [4096][1024] f32 -> bf16 row-major ----
__global__ void cvt_x_kernel(const float* __restrict__ x, unsigned short* __restrict__ xb) {
  int i = blockIdx.x * blockDim.x + threadIdx.x;
  float4 v = reinterpret_cast<const float4*>(x)[i];
  ushort4 o;
  o.x = f2bf(v.x); o.y = f2bf(v.y); o.z = f2bf(v.z); o.w = f2bf(v.w);
  reinterpret_cast<ushort4*>(xb)[i] = o;
}

// ---- convert W [1024][1024] f32 -> Wt bf16 with Wt[n][k] = W[k][n] ----
__global__ void cvt_w_transpose_kernel(const float* __restrict__ w0, const float* __restrict__ w1,
                                       const float* __restrict__ w2, unsigned short* __restrict__ wt) {
  __shared__ float tile[32][33];
  const float* w = blockIdx.z == 0 ? w0 : (blockIdx.z == 1 ? w1 : w2);
  unsigned short* o = wt + (size_t)blockIdx.z * D_ * N_;
  int kbase = blockIdx.y * 32, nbase = blockIdx.x * 32;
#pragma unroll
  for (int i = 0; i < 4; i++)
    tile[threadIdx.y + i*8][threadIdx.x] =
        w[(size_t)(kbase + threadIdx.y + i*8) * N_ + nbase + threadIdx.x];
  __syncthreads();
#pragma unroll
  for (int i = 0; i < 4; i++)
    o[(size_t)(nbase + threadIdx.y + i*8) * D_ + kbase + threadIdx.x] =
        f2bf(tile[threadIdx.x][threadIdx.y + i*8]);
}

// ---- QKV GEMM, m97-style (unchanged from round 2 — at structure ceiling) ----
__global__ __launch_bounds__(256) void qkv_gemm_kernel(const unsigned short* __restrict__ xb,
                                                       const unsigned short* __restrict__ wt,
                                                       unsigned short* __restrict__ qkv) {
  __shared__ __align__(16) unsigned short As[128 * 64];
  __shared__ __align__(16) unsigned short Bs[128 * 64];
  const unsigned short* w = wt + (size_t)blockIdx.z * D_ * N_;
  unsigned short* out = qkv + (size_t)blockIdx.z * HSZ;
  int lane = threadIdx.x & 63, wave = threadIdx.x >> 6;
  int lr = lane & 15, lk = lane >> 4;
  int mblk = blockIdx.y * 128, nblk = blockIdx.x * 128;
  int wm = (wave >> 1) * 64, wn = (wave & 1) * 64;

  int srow0 = wave * 32 + (lane >> 3);
  int scol = lane & 7;
  f32x4 acc[4][4] = {};

  for (int kk = 0; kk < D_; kk += 64) {
    __syncthreads();
#pragma unroll
    for (int it = 0; it < 4; it++) {
      int row = srow0 + it * 8;
      int ce = (scol ^ (row & 7)) * 8;
      gll16(xb + (size_t)(mblk + row) * D_ + kk + ce,
            (void*)(As + (size_t)(wave * 4 + it) * 512));
      gll16(w  + (size_t)(nblk + row) * D_ + kk + ce,
            (void*)(Bs + (size_t)(wave * 4 + it) * 512));
    }
    __syncthreads();

    short8 a[2][4], b[2][4];
#pragma unroll
    for (int i = 0; i < 4; i++) {
      int row = wm + i * 16 + lr;
      const char* rp = (const char*)As + row * 128;
#pragma unroll
      for (int ks = 0; ks < 2; ks++)
        a[ks][i] = *reinterpret_cast<const short8*>(rp + ((((ks*4 + lk) ^ (row & 7))) << 4));
    }
#pragma unroll
    for (int j = 0; j < 4; j++) {
      int row = wn + j * 16 + lr;
      const char* rp = (const char*)Bs + row * 128;
#pragma unroll
      for (int ks = 0; ks < 2; ks++)
        b[ks][j] = *reinterpret_cast<const short8*>(rp + ((((ks*4 + lk) ^ (row & 7))) << 4));
    }
#pragma unroll
    for (int ks = 0; ks < 2; ks++)
#pragma unroll
      for (int i = 0; i < 4; i++)
#pragma unroll
        for (int j = 0; j < 4; j++)
          acc[i][j] = __builtin_amdgcn_mfma_f32_16x16x32_bf16(a[ks][i], b[ks][j], acc[i][j], 0, 0, 0);
  }

#pragma unroll
  for (int i = 0; i < 4; i++)
#pragma unroll
    for (int j = 0; j < 4; j++)
#pragma unroll
      for (int r = 0; r < 4; r++) {
        int m = mblk + wm + i*16 + lk*4 + r;
        int n = nblk + wn + j*16 + lr;
        int bb = m >> 11, s = m & (S_-1), h = n >> 6, d = n & (HD_-1);
        out[(((size_t)bb * H_ + h) * S_ + s) * HD_ + d] = f2bf(acc[i][j][r]);
      }
}

// ---- Flash attention, m214-style: 4 waves x 32 q-rows, 32x32x16 MFMA,
//      swapped QK^T (S^T = K·Q^T) => in-register softmax, P never hits LDS ----
__global__ __launch_bounds__(256) void attn_kernel(const unsigned short* __restrict__ qkv,
                                                   float* __restrict__ out) {
  int bh = blockIdx.y;
  const unsigned short* Q = qkv +            (size_t)bh * S_ * HD_;
  const unsigned short* K = qkv + HSZ   +    (size_t)bh * S_ * HD_;
  const unsigned short* V = qkv + 2*HSZ +    (size_t)bh * S_ * HD_;
  int lane = threadIdx.x & 63, wave = threadIdx.x >> 6;
  int ql = lane & 31, hi = lane >> 5;
  int qbase = blockIdx.x * 128 + wave * 32;   // this wave's 32 q rows

  __shared__ __align__(16) unsigned short vt[64 * 64];   // V^T tile, swizzled rows
  char* vb = (char*)vt;

  // Q fragments (B-operand layout): col=ql, k=hi*8+e -> d = ds*16 + hi*8 + e
  short8 qf[4];
#pragma unroll
  for (int ds = 0; ds < 4; ds++)
    qf[ds] = *reinterpret_cast<const short8*>(Q + (size_t)(qbase + ql) * HD_ + ds*16 + hi*8);

  f32x16 oacc[2] = {};     // O^T: col q=ql, rows d = dh*32 + (reg&3)+8*(reg>>2)+4*hi
  float m = -INFINITY, lsum = 0.f;

  int vkv = threadIdx.x >> 2;          // kv row this thread stages: 0..63
  int vdc = (threadIdx.x & 3) * 16;    // d-chunk: 0,16,32,48

  for (int kt = 0; kt < S_/64; kt++) {
    int kc0 = kt * 64;
    __syncthreads();                   // previous PV done reading vt
    // stage V^T (swizzled scatter; conflict-free: (d>>3) term separates d-groups)
    {
      const unsigned short* vr = V + (size_t)(kc0 + vkv) * HD_ + vdc;
      short8 v0 = *reinterpret_cast<const short8*>(vr);
      short8 v1 = *reinterpret_cast<const short8*>(vr + 8);
#pragma unroll
      for (int i = 0; i < 8; i++) {
        int d0 = vdc + i, d1 = vdc + 8 + i;
        *(unsigned short*)(vb + d0*128 + ((vkv*2) ^ SWZ(d0))) = (unsigned short)v0[i];
        *(unsigned short*)(vb + d1*128 + ((vkv*2) ^ SWZ(d1))) = (unsigned short)v1[i];
      }
    }
    // QK^T (swapped): sacc[kh] = S^T[kv = kh*32 + crow][q = ql]
    f32x16 sacc[2] = {};
#pragma unroll
    for (int kh = 0; kh < 2; kh++)
#pragma unroll
      for (int ds = 0; ds < 4; ds++) {
        short8 kf = *reinterpret_cast<const short8*>(
            K + (size_t)(kc0 + kh*32 + ql) * HD_ + ds*16 + hi*8);
        sacc[kh] = __builtin_amdgcn_mfma_f32_32x32x16_bf16(kf, qf[ds], sacc[kh], 0, 0, 0);
      }
    __syncthreads();                   // vt ready

    // in-register online softmax (lane + partner l^32 hold the full 64-kv row)
    float mx = sacc[0][0];
#pragma unroll
    for (int r = 1; r < 16; r++) mx = fmaxf(mx, sacc[0][r]);
#pragma unroll
    for (int r = 0; r < 16; r++) mx = fmaxf(mx, sacc[1][r]);
    mx = fmaxf(mx, __shfl_xor(mx, 32));
    float mnew = fmaxf(m, mx);
    float corr = __expf((m - mnew) * 0.125f);
    float ms = mnew * 0.125f;
    m = mnew;
    float rsum = 0.f;
#pragma unroll
    for (int kh = 0; kh < 2; kh++)
#pragma unroll
      for (int r = 0; r < 16; r++) {
        float p = __expf(fmaf(sacc[kh][r], 0.125f, -ms));
        sacc[kh][r] = p;
        rsum += p;
      }
    rsum += __shfl_xor(rsum, 32);
    lsum = lsum * corr + rsum;
#pragma unroll
    for (int dh = 0; dh < 2; dh++)
#pragma unroll
      for (int r = 0; r < 16; r++) oacc[dh][r] *= corr;

    // P^T -> bf16 frags (T12: cvt_pk + permlane32_swap), then PV
#pragma unroll
    for (int ks = 0; ks < 4; ks++) {
      int o = (ks & 1) * 8;
      unsigned int w0, w1, w2, w3;
      if (ks < 2) {
        w0 = cvt_pk_bf16(sacc[0][o+0], sacc[0][o+1]);
        w1 = cvt_pk_bf16(sacc[0][o+2], sacc[0][o+3]);
        w2 = cvt_pk_bf16(sacc[0][o+4], sacc[0][o+5]);
        w3 = cvt_pk_bf16(sacc[0][o+6], sacc[0][o+7]);
      } else {
        w0 = cvt_pk_bf16(sacc[1][o+0], sacc[1][o+1]);
        w1 = cvt_pk_bf16(sacc[1][o+2], sacc[1][o+3]);
        w2 = cvt_pk_bf16(sacc[1][o+4], sacc[1][o+5]);
        w3 = cvt_pk_bf16(sacc[1][o+6], sacc[1][o+7]);
      }
      // swap pairs (w0,w2) and (w1,w3): after, words [w0,w1,w2,w3] = kv e01,e23,e45,e67
      asm("v_permlane32_swap_b32 %0, %1" : "+v"(w0), "+v"(w2));
      asm("v_permlane32_swap_b32 %0, %1" : "+v"(w1), "+v"(w3));
      union { unsigned int u[4]; short8 s; } pf;
      pf.u[0] = w0; pf.u[1] = w1; pf.u[2] = w2; pf.u[3] = w3;
#pragma unroll
      for (int dh = 0; dh < 2; dh++) {
        int row = dh*32 + ql;
        short8 vf = *reinterpret_cast<const short8*>(
            vb + row*128 + ((ks*32 + hi*16) ^ SWZ(row)));
        oacc[dh] = __builtin_amdgcn_mfma_f32_32x32x16_bf16(vf, pf.s, oacc[dh], 0, 0, 0);
      }
    }
  }

  // epilogue: O[s][d] = O^T / lsum
  float inv = 1.0f / lsum;
  int b0 = bh >> 4, h = bh & (H_-1);
  int s = qbase + ql;
  float* orow = out + ((size_t)b0 * S_ + s) * N_ + h * HD_;
#pragma unroll
  for (int dh = 0; dh < 2; dh++)
#pragma unroll
    for (int r = 0; r < 16; r++) {
      int d = dh*32 + (r & 3) + 8*(r >> 2) + 4*hi;
      orow[d] = oacc[dh][r] * inv;
    }
}

extern "C" void kernel_launch(void* const* d_in, const int* in_sizes, int n_in,
                              void* d_out, int out_size, void* d_ws, size_t ws_size,
                              hipStream_t stream) {
  const float* X  = (const float*)d_in[0];
  const float* Wq = (const float*)d_in[1];
  const float* Wk = (const float*)d_in[2];
  const float* Wv = (const float*)d_in[3];
  float* out = (float*)d_out;

  unsigned short* Xb  = (unsigned short*)d_ws;
  unsigned short* Wt  = Xb + (size_t)M_ * D_;
  unsigned short* QKV = Wt + (size_t)3 * D_ * N_;

  cvt_x_kernel<<<(M_*D_)/(256*4), 256, 0, stream>>>(X, Xb);
  cvt_w_transpose_kernel<<<dim3(N_/32, D_/32, 3), dim3(32, 8), 0, stream>>>(Wq, Wk, Wv, Wt);
  qkv_gemm_kernel<<<dim3(N_/128, M_/128, 3), 256, 0, stream>>>(Xb, Wt, QKV);
  attn_kernel<<<dim3(S_/128, B_*H_), 256, 0, stream>>>(QKV, out);
}

// Round 4
// 123.424 us; speedup vs baseline: 2.3023x; 1.1557x over previous
//
#include <hip/hip_runtime.h>

typedef __attribute__((ext_vector_type(8))) short short8;
typedef __attribute__((ext_vector_type(4))) float f32x4;
typedef __attribute__((ext_vector_type(16))) float f32x16;

#define B_  2
#define S_  2048
#define D_  1024
#define H_  16
#define HD_ 64
#define M_  (B_*S_)                    // 4096
#define N_  (H_*HD_)                   // 1024
#define HSZ ((size_t)B_*H_*S_*HD_)     // 4194304 elements per Q/K/V

// 0.125 * log2(e): QK^T scores land in log2 domain (exp2 = single v_exp_f32)
#define QSCALE 0.18033688011112042f

__device__ __forceinline__ unsigned short f2bf(float f) {
  unsigned int u = __float_as_uint(f);
  u += 0x7fffu + ((u >> 16) & 1u);
  return (unsigned short)(u >> 16);
}

__device__ __forceinline__ unsigned int cvt_pk_bf16(float lo, float hi) {
  unsigned int r;
  asm("v_cvt_pk_bf16_f32 %0, %1, %2" : "=v"(r) : "v"(lo), "v"(hi));
  return r;
}

__device__ __forceinline__ float exp2_fast(float x) {
  float r;
  asm("v_exp_f32 %0, %1" : "=v"(r) : "v"(x));
  return r;
}

__device__ __forceinline__ void gll16(const void* g, void* l) {
  __builtin_amdgcn_global_load_lds(
      (const __attribute__((address_space(1))) void*)g,
      (__attribute__((address_space(3))) void*)l, 16, 0, 0);
}

// ---- convert X [4096][1024] f32 -> bf16 row-major ----
__global__ void cvt_x_kernel(const float* __restrict__ x, unsigned short* __restrict__ xb) {
  int i = blockIdx.x * blockDim.x + threadIdx.x;
  float4 v = reinterpret_cast<const float4*>(x)[i];
  ushort4 o;
  o.x = f2bf(v.x); o.y = f2bf(v.y); o.z = f2bf(v.z); o.w = f2bf(v.w);
  reinterpret_cast<ushort4*>(xb)[i] = o;
}

// ---- convert W [1024][1024] f32 -> Wt bf16 with Wt[n][k] = W[k][n] ----
__global__ void cvt_w_transpose_kernel(const float* __restrict__ w0, const float* __restrict__ w1,
                                       const float* __restrict__ w2, unsigned short* __restrict__ wt) {
  __shared__ float tile[32][33];
  const float* w = blockIdx.z == 0 ? w0 : (blockIdx.z == 1 ? w1 : w2);
  unsigned short* o = wt + (size_t)blockIdx.z * D_ * N_;
  int kbase = blockIdx.y * 32, nbase = blockIdx.x * 32;
#pragma unroll
  for (int i = 0; i < 4; i++)
    tile[threadIdx.y + i*8][threadIdx.x] =
        w[(size_t)(kbase + threadIdx.y + i*8) * N_ + nbase + threadIdx.x];
  __syncthreads();
#pragma unroll
  for (int i = 0; i < 4; i++)
    o[(size_t)(nbase + threadIdx.y + i*8) * D_ + kbase + threadIdx.x] =
        f2bf(tile[threadIdx.x][threadIdx.y + i*8]);
}

// ---- QKV GEMM, m97-style. z==0: Q scaled by QSCALE. z==2: V written transposed
//      as Vt[b][h][d][s] (packed ushort4 along s). ----
__global__ __launch_bounds__(256) void qkv_gemm_kernel(const unsigned short* __restrict__ xb,
                                                       const unsigned short* __restrict__ wt,
                                                       unsigned short* __restrict__ qkv) {
  __shared__ __align__(16) unsigned short As[128 * 64];
  __shared__ __align__(16) unsigned short Bs[128 * 64];
  const unsigned short* w = wt + (size_t)blockIdx.z * D_ * N_;
  unsigned short* out = qkv + (size_t)blockIdx.z * HSZ;
  int lane = threadIdx.x & 63, wave = threadIdx.x >> 6;
  int lr = lane & 15, lk = lane >> 4;
  int mblk = blockIdx.y * 128, nblk = blockIdx.x * 128;
  int wm = (wave >> 1) * 64, wn = (wave & 1) * 64;

  int srow0 = wave * 32 + (lane >> 3);
  int scol = lane & 7;
  f32x4 acc[4][4] = {};

  for (int kk = 0; kk < D_; kk += 64) {
    __syncthreads();
#pragma unroll
    for (int it = 0; it < 4; it++) {
      int row = srow0 + it * 8;
      int ce = (scol ^ (row & 7)) * 8;
      gll16(xb + (size_t)(mblk + row) * D_ + kk + ce,
            (void*)(As + (size_t)(wave * 4 + it) * 512));
      gll16(w  + (size_t)(nblk + row) * D_ + kk + ce,
            (void*)(Bs + (size_t)(wave * 4 + it) * 512));
    }
    __syncthreads();

    short8 a[2][4], b[2][4];
#pragma unroll
    for (int i = 0; i < 4; i++) {
      int row = wm + i * 16 + lr;
      const char* rp = (const char*)As + row * 128;
#pragma unroll
      for (int ks = 0; ks < 2; ks++)
        a[ks][i] = *reinterpret_cast<const short8*>(rp + ((((ks*4 + lk) ^ (row & 7))) << 4));
    }
#pragma unroll
    for (int j = 0; j < 4; j++) {
      int row = wn + j * 16 + lr;
      const char* rp = (const char*)Bs + row * 128;
#pragma unroll
      for (int ks = 0; ks < 2; ks++)
        b[ks][j] = *reinterpret_cast<const short8*>(rp + ((((ks*4 + lk) ^ (row & 7))) << 4));
    }
#pragma unroll
    for (int ks = 0; ks < 2; ks++)
#pragma unroll
      for (int i = 0; i < 4; i++)
#pragma unroll
        for (int j = 0; j < 4; j++)
          acc[i][j] = __builtin_amdgcn_mfma_f32_16x16x32_bf16(a[ks][i], b[ks][j], acc[i][j], 0, 0, 0);
  }

  if (blockIdx.z == 2) {
    // V^T: Vt[((bb*H+h)*HD + d)*S + s], 4 consecutive s per lane packed
#pragma unroll
    for (int i = 0; i < 4; i++) {
      int m0 = mblk + wm + i*16 + lk*4;
      int bb = m0 >> 11, s0 = m0 & (S_-1);
#pragma unroll
      for (int j = 0; j < 4; j++) {
        int n = nblk + wn + j*16 + lr;
        int h = n >> 6, d = n & (HD_-1);
        ushort4 pk;
        pk.x = f2bf(acc[i][j][0]); pk.y = f2bf(acc[i][j][1]);
        pk.z = f2bf(acc[i][j][2]); pk.w = f2bf(acc[i][j][3]);
        *reinterpret_cast<ushort4*>(out + ((size_t)(bb*H_ + h)*HD_ + d)*S_ + s0) = pk;
      }
    }
  } else {
    float qs = (blockIdx.z == 0) ? QSCALE : 1.0f;
#pragma unroll
    for (int i = 0; i < 4; i++)
#pragma unroll
      for (int j = 0; j < 4; j++)
#pragma unroll
        for (int r = 0; r < 4; r++) {
          int m = mblk + wm + i*16 + lk*4 + r;
          int n = nblk + wn + j*16 + lr;
          int bb = m >> 11, s = m & (S_-1), h = n >> 6, d = n & (HD_-1);
          out[(((size_t)bb * H_ + h) * S_ + s) * HD_ + d] = f2bf(acc[i][j][r] * qs);
        }
  }
}

// ---- Flash attention: 4 waves x 32 q-rows, swapped QK^T, in-register softmax,
//      double-buffered K/V LDS tiles staged via global_load_lds (T3 2-phase),
//      log2-domain scores + defer-max (T13), XCD-chunked block swizzle (T1). ----
__global__ __launch_bounds__(256) void attn_kernel(const unsigned short* __restrict__ qkv,
                                                   float* __restrict__ out) {
  // XCD-chunked swizzle: 512 blocks, 64 consecutive work-items per XCD ->
  // all 16 q-tiles of a bh group land on the same XCD (K/V L2-local).
  int hid = blockIdx.x;
  int wrk = (hid & 7) * 64 + (hid >> 3);
  int bh = wrk >> 4, qtile = wrk & 15;

  const unsigned short* Q  = qkv +            (size_t)bh * S_ * HD_;
  const unsigned short* K  = qkv + HSZ   +    (size_t)bh * S_ * HD_;
  const unsigned short* Vt = qkv + 2*HSZ +    (size_t)bh * HD_ * S_;  // [d][s]
  int lane = threadIdx.x & 63, wave = threadIdx.x >> 6;
  int ql = lane & 31, hi = lane >> 5;
  int qbase = qtile * 128 + wave * 32;

  __shared__ __align__(16) unsigned short Ks[2][64 * 64];  // [kv][d], swizzled
  __shared__ __align__(16) unsigned short Vs[2][64 * 64];  // [d][kv], swizzled

  // staging geometry: chunk ci = it*256 + tid -> row = ci>>3, col c = ci&7
  int tid = threadIdx.x;

  // Q fragments (pre-scaled by QSCALE in GEMM): B-operand, col=ql, k=hi*8+e
  short8 qf[4];
#pragma unroll
  for (int ds = 0; ds < 4; ds++)
    qf[ds] = *reinterpret_cast<const short8*>(Q + (size_t)(qbase + ql) * HD_ + ds*16 + hi*8);

  f32x16 oacc[2] = {};
  float m = -INFINITY, lsum = 0.f;

  // prologue: stage tile 0 into buffer 0
#pragma unroll
  for (int it = 0; it < 2; it++) {
    int ci = it * 256 + tid, row = ci >> 3, c = ci & 7;
    int ce = (c ^ (row & 7)) * 8;
    gll16(K  + (size_t)row * HD_ + ce, (void*)(Ks[0] + (size_t)ci * 8));
    gll16(Vt + (size_t)row * S_  + ce, (void*)(Vs[0] + (size_t)ci * 8));
  }

  int buf = 0;
  for (int kt = 0; kt < S_/64; kt++) {
    __syncthreads();   // stage(kt) visible; prev iteration's reads of buf^1 done
    if (kt < S_/64 - 1) {
      int kc1 = (kt + 1) * 64;
#pragma unroll
      for (int it = 0; it < 2; it++) {
        int ci = it * 256 + tid, row = ci >> 3, c = ci & 7;
        int ce = (c ^ (row & 7)) * 8;
        gll16(K  + (size_t)(kc1 + row) * HD_ + ce, (void*)(Ks[buf^1] + (size_t)ci * 8));
        gll16(Vt + (size_t)row * S_ + kc1 + ce,    (void*)(Vs[buf^1] + (size_t)ci * 8));
      }
    }

    // QK^T (swapped): sacc[kh][r] = S^T[kv = kh*32 + crow(r,hi)][q = ql], log2 domain
    f32x16 sacc[2] = {};
    __builtin_amdgcn_s_setprio(1);
#pragma unroll
    for (int kh = 0; kh < 2; kh++) {
      int row = kh*32 + ql;
      const char* rp = (const char*)Ks[buf] + row * 128;
#pragma unroll
      for (int ds = 0; ds < 4; ds++) {
        short8 kf = *reinterpret_cast<const short8*>(rp + (((ds*2 + hi) ^ (row & 7)) << 4));
        sacc[kh] = __builtin_amdgcn_mfma_f32_32x32x16_bf16(kf, qf[ds], sacc[kh], 0, 0, 0);
      }
    }
    __builtin_amdgcn_s_setprio(0);

    // ---- softmax (in-register, tree reductions, defer-max) ----
    float tm[16];
#pragma unroll
    for (int r = 0; r < 16; r++) tm[r] = fmaxf(sacc[0][r], sacc[1][r]);
#pragma unroll
    for (int st = 8; st > 0; st >>= 1)
#pragma unroll
      for (int r = 0; r < st; r++) tm[r] = fmaxf(tm[r], tm[r + st]);
    float mx = fmaxf(tm[0], __shfl_xor(tm[0], 32));
    if (__any(mx - m > 8.0f)) {          // T13: rescale only when max grew
      float mnew = fmaxf(m, mx);
      float corr = exp2_fast(m - mnew);
      m = mnew;
      lsum *= corr;
#pragma unroll
      for (int dh = 0; dh < 2; dh++)
#pragma unroll
        for (int r = 0; r < 16; r++) oacc[dh][r] *= corr;
    }
#pragma unroll
    for (int kh = 0; kh < 2; kh++)
#pragma unroll
      for (int r = 0; r < 16; r++)
        sacc[kh][r] = exp2_fast(sacc[kh][r] - m);
    float ts[16];
#pragma unroll
    for (int r = 0; r < 16; r++) ts[r] = sacc[0][r] + sacc[1][r];
#pragma unroll
    for (int st = 8; st > 0; st >>= 1)
#pragma unroll
      for (int r = 0; r < st; r++) ts[r] += ts[r + st];
    lsum += ts[0] + __shfl_xor(ts[0], 32);

    // ---- P^T -> bf16 (T12) + PV ----
#pragma unroll
    for (int ks = 0; ks < 4; ks++) {
      int o = (ks & 1) * 8;
      unsigned int w0, w1, w2, w3;
      if (ks < 2) {
        w0 = cvt_pk_bf16(sacc[0][o+0], sacc[0][o+1]);
        w1 = cvt_pk_bf16(sacc[0][o+2], sacc[0][o+3]);
        w2 = cvt_pk_bf16(sacc[0][o+4], sacc[0][o+5]);
        w3 = cvt_pk_bf16(sacc[0][o+6], sacc[0][o+7]);
      } else {
        w0 = cvt_pk_bf16(sacc[1][o+0], sacc[1][o+1]);
        w1 = cvt_pk_bf16(sacc[1][o+2], sacc[1][o+3]);
        w2 = cvt_pk_bf16(sacc[1][o+4], sacc[1][o+5]);
        w3 = cvt_pk_bf16(sacc[1][o+6], sacc[1][o+7]);
      }
      asm("v_permlane32_swap_b32 %0, %1" : "+v"(w0), "+v"(w2));
      asm("v_permlane32_swap_b32 %0, %1" : "+v"(w1), "+v"(w3));
      union { unsigned int u[4]; short8 s; } pf;
      pf.u[0] = w0; pf.u[1] = w1; pf.u[2] = w2; pf.u[3] = w3;
      __builtin_amdgcn_s_setprio(1);
#pragma unroll
      for (int dh = 0; dh < 2; dh++) {
        int row = dh*32 + ql;
        short8 vf = *reinterpret_cast<const short8*>(
            (const char*)Vs[buf] + row * 128 + (((ks*2 + hi) ^ (row & 7)) << 4));
        oacc[dh] = __builtin_amdgcn_mfma_f32_32x32x16_bf16(vf, pf.s, oacc[dh], 0, 0, 0);
      }
      __builtin_amdgcn_s_setprio(0);
    }
    buf ^= 1;
  }

  // epilogue: O[s][d] = O^T / lsum, packed float4 stores
  float inv = 1.0f / lsum;
  int b0 = bh >> 4, h = bh & (H_-1);
  int s = qbase + ql;
  float* orow = out + ((size_t)b0 * S_ + s) * N_ + h * HD_;
#pragma unroll
  for (int dh = 0; dh < 2; dh++)
#pragma unroll
    for (int a = 0; a < 4; a++) {
      float4 vv;
      vv.x = oacc[dh][a*4+0] * inv; vv.y = oacc[dh][a*4+1] * inv;
      vv.z = oacc[dh][a*4+2] * inv; vv.w = oacc[dh][a*4+3] * inv;
      *reinterpret_cast<float4*>(orow + dh*32 + 8*a + 4*hi) = vv;
    }
}

extern "C" void kernel_launch(void* const* d_in, const int* in_sizes, int n_in,
                              void* d_out, int out_size, void* d_ws, size_t ws_size,
                              hipStream_t stream) {
  const float* X  = (const float*)d_in[0];
  const float* Wq = (const float*)d_in[1];
  const float* Wk = (const float*)d_in[2];
  const float* Wv = (const float*)d_in[3];
  float* out = (float*)d_out;

  unsigned short* Xb  = (unsigned short*)d_ws;
  unsigned short* Wt  = Xb + (size_t)M_ * D_;
  unsigned short* QKV = Wt + (size_t)3 * D_ * N_;

  cvt_x_kernel<<<(M_*D_)/(256*4), 256, 0, stream>>>(X, Xb);
  cvt_w_transpose_kernel<<<dim3(N_/32, D_/32, 3), dim3(32, 8), 0, stream>>>(Wq, Wk, Wv, Wt);
  qkv_gemm_kernel<<<dim3(N_/128, M_/128, 3), 256, 0, stream>>>(Xb, Wt, QKV);
  attn_kernel<<<(S_/128) * (B_*H_), 256, 0, stream>>>(QKV, out);
}